// Round 20
// baseline (115.415 us; speedup 1.0000x reference)
//
#include <hip/hip_runtime.h>
#include <hip/hip_fp16.h>

#define PTAB_STRIDE 64   // halves per row = 128 B
#define TANH_SCALE 2.885390081777927f   // 2 * log2(e): folds exp(2a) -> exp2(a')

typedef float    f32x4 __attribute__((ext_vector_type(4)));
typedef _Float16 half8 __attribute__((ext_vector_type(8)));
typedef _Float16 h2    __attribute__((ext_vector_type(2)));

__device__ __forceinline__ h2 u2h2(unsigned int u) {
    union { unsigned int u; h2 h; } c; c.u = u; return c.h;
}

__device__ __forceinline__ float fdot2x(h2 a, h2 b, float c) {
#if __has_builtin(__builtin_amdgcn_fdot2)
    return __builtin_amdgcn_fdot2(a, b, c, false);
#else
    return c + (float)a[0] * (float)b[0] + (float)a[1] * (float)b[1];
#endif
}

__device__ __forceinline__ float clamp26(float a) {
#if __has_builtin(__builtin_amdgcn_fmed3f)
    return __builtin_amdgcn_fmed3f(a, -26.f, 26.f);   // 1 VALU op
#else
    return fminf(26.f, fmaxf(-26.f, a));
#endif
}

// ---------------------------------------------------------------------------
// Kernel 0: pack B-fragments (W^T, fp16, zero-padded to K=320 x N=64) in the
// exact mfma_f32_16x16x32_f16 per-lane layout, + fused bias table.
// ---------------------------------------------------------------------------
__global__ __launch_bounds__(64) void prep_kernel(
    const float* __restrict__ Wih, const float* __restrict__ bih,
    const float* __restrict__ bhh, __half* __restrict__ Bfrag,
    float* __restrict__ bias64)
{
    const int lane = threadIdx.x;
    const int st   = blockIdx.x;
    if (st == 40) {
        if (lane < 64) bias64[lane] = (lane < 50) ? bih[lane] + bhh[lane] : 0.f;
        return;
    }
    const int s  = st >> 2, t = st & 3;
    const int n  = 16 * t + (lane & 15);
    const int kb = lane >> 4;
    half8 v;
    #pragma unroll
    for (int j = 0; j < 8; ++j) {
        const int k = 32 * s + 8 * kb + j;
        float w = 0.f;
        if (n < 50 && k < 300) w = Wih[n * 300 + k];
        v[j] = (_Float16)w;
    }
    *reinterpret_cast<half8*>(Bfrag + ((size_t)st * 64 + lane) * 8) = v;
}

// ---------------------------------------------------------------------------
// Phase 1: ptab[v][h] = fp16( TANH_SCALE*(dot(emb[v,:],W_ih[h,:])+b) )
// 782 blocks x 4 waves; one wave per 16 vocab rows, 4 N-tile accumulators,
// 40 MFMAs. NEW vs r16: explicit next-K-step register prefetch — the s+1
// emb loads are issued before the s-step cvts+MFMAs (~120 cyc of cover), so
// HBM latency hides under compute instead of relying on 3-waves/SIMD TLP.
// TANH_SCALE folded into the epilogue (off critical path) so the rnn step
// can use exp2 directly.
// ---------------------------------------------------------------------------
__global__ __launch_bounds__(256) void ptab_mfma(
    const float* __restrict__ emb, const __half* __restrict__ Bfrag,
    const float* __restrict__ bias64, __half* __restrict__ ptab)
{
    const int lane = threadIdx.x & 63;
    const int wid  = threadIdx.x >> 6;
    const int wgid = blockIdx.x * 4 + wid;
    if (wgid >= 3125) return;
    const int v0   = wgid * 16;
    const int m    = lane & 15;
    const int kb   = lane >> 4;
    const float4* E4 = (const float4*)(emb + (size_t)(v0 + m) * 300);
    const half8* BF  = reinterpret_cast<const half8*>(Bfrag);

    f32x4 acc[4];
    #pragma unroll
    for (int t = 0; t < 4; ++t) acc[t] = (f32x4){0.f, 0.f, 0.f, 0.f};

    float4 c0 = E4[2 * kb], c1 = E4[2 * kb + 1];
    #pragma unroll
    for (int s = 0; s < 9; ++s) {
        float4 n0, n1;
        if (s < 8) {                       // prefetch K-step s+1
            n0 = E4[8 * (s + 1) + 2 * kb];
            n1 = E4[8 * (s + 1) + 2 * kb + 1];
        }
        half8 a;
        a[0] = (_Float16)c0.x; a[1] = (_Float16)c0.y;
        a[2] = (_Float16)c0.z; a[3] = (_Float16)c0.w;
        a[4] = (_Float16)c1.x; a[5] = (_Float16)c1.y;
        a[6] = (_Float16)c1.z; a[7] = (_Float16)c1.w;
        #pragma unroll
        for (int t = 0; t < 4; ++t)
            acc[t] = __builtin_amdgcn_mfma_f32_16x16x32_f16(
                a, BF[(4 * s + t) * 64 + lane], acc[t], 0, 0, 0);
        if (s < 8) { c0 = n0; c1 = n1; }
    }
    {   // tail K-step s=9: k = 288..319, valid only k < 300
        const float* Erow = (const float*)E4;
        half8 a;
        #pragma unroll
        for (int j = 0; j < 8; ++j) {
            const int k = 288 + 8 * kb + j;
            float e = 0.f;
            if (k < 300) e = Erow[k];
            a[j] = (_Float16)e;
        }
        #pragma unroll
        for (int t = 0; t < 4; ++t)
            acc[t] = __builtin_amdgcn_mfma_f32_16x16x32_f16(
                a, BF[(36 + t) * 64 + lane], acc[t], 0, 0, 0);
    }

    const int nn = lane & 15;
    #pragma unroll
    for (int t = 0; t < 4; ++t) {
        const float bt = bias64[16 * t + nn];
        #pragma unroll
        for (int r = 0; r < 4; ++r)
            ptab[(size_t)(v0 + 4 * kb + r) * PTAB_STRIDE + 16 * t + nn] =
                (__half)((acc[t][r] + bt) * TANH_SCALE);
    }
}

// ---------------------------------------------------------------------------
// Phase 2: recurrence + head. One sequence per wave, 256 waves (1/CU).
// r16 structure (measured floor: three broadcast mechanisms converge at
// ~400 cyc/step): per step 1 ds_write_b16 + staged uniform-broadcast reads
// interleaved with 4-chain v_dot2_f32_f16, then tanh. W_hh pre-scaled by
// TANH_SCALE so tanh = fma(-2, rcp(exp2(a)+1), 1) with NO mul before exp
// (the only change vs r16; saves one serial VALU op per step).
// ---------------------------------------------------------------------------
__global__ __launch_bounds__(64, 1) void rnn_kernel(
    const int* __restrict__ tokens, const __half* __restrict__ ptab,
    const float* __restrict__ Whh,
    const float* __restrict__ Wfc, const float* __restrict__ bfc,
    float* __restrict__ out)
{
    __shared__ int stok[544];
    __shared__ __align__(16) _Float16 hbuf[64];
    const int lane = threadIdx.x;
    const int b    = blockIdx.x;
    const int hc   = lane < 50 ? lane : 49;

    #pragma unroll
    for (int k = 0; k < 8; ++k)
        stok[lane + 64 * k] = tokens[b * 512 + lane + 64 * k];
    if (lane < 32) stok[512 + lane] = 0;     // pad: token 0 -> valid row
    __syncthreads();

    // W_hh row for this lane, pre-scaled by TANH_SCALE: 25 packed fp16 pairs.
    unsigned int wh_u[25];
    #pragma unroll
    for (int j = 0; j < 25; ++j) {
        float2 w2 = *(const float2*)(Whh + hc * 50 + 2 * j);
        union { h2 h; unsigned int u; } c;
        c.h = (h2){(_Float16)(w2.x * TANH_SCALE), (_Float16)(w2.y * TANH_SCALE)};
        wh_u[j] = c.u;
    }

    float h = 0.f;

#define GA(T) ptab[(size_t)(T) * PTAB_STRIDE + lane]

    __half x0 = GA(stok[0]), x1 = GA(stok[1]), x2 = GA(stok[2]), x3 = GA(stok[3]);
    __half x4 = GA(stok[4]), x5 = GA(stok[5]), x6 = GA(stok[6]), x7 = GA(stok[7]);

#define SL(Q, i) __builtin_shufflevector(Q, Q, 2*(i), 2*(i)+1)
#define WH(j) u2h2(wh_u[j])

#define RNN_STEP(XV)                                                         \
    {                                                                        \
        hbuf[lane] = (_Float16)h;          /* ds_write_b16, in-order */      \
        const half8* H8 = (const half8*)hbuf;                                \
        half8 q0 = H8[0], q1 = H8[1];                                        \
        float s0 = 0.f, s1 = 0.f, s2 = 0.f, s3 = 0.f;                        \
        s0 = fdot2x(SL(q0,0), WH(0),  s0); s1 = fdot2x(SL(q0,1), WH(1),  s1);\
        s2 = fdot2x(SL(q0,2), WH(2),  s2); s3 = fdot2x(SL(q0,3), WH(3),  s3);\
        s0 = fdot2x(SL(q1,0), WH(4),  s0); s1 = fdot2x(SL(q1,1), WH(5),  s1);\
        s2 = fdot2x(SL(q1,2), WH(6),  s2); s3 = fdot2x(SL(q1,3), WH(7),  s3);\
        half8 q2 = H8[2], q3 = H8[3];                                        \
        s0 = fdot2x(SL(q2,0), WH(8),  s0); s1 = fdot2x(SL(q2,1), WH(9),  s1);\
        s2 = fdot2x(SL(q2,2), WH(10), s2); s3 = fdot2x(SL(q2,3), WH(11), s3);\
        s0 = fdot2x(SL(q3,0), WH(12), s0); s1 = fdot2x(SL(q3,1), WH(13), s1);\
        s2 = fdot2x(SL(q3,2), WH(14), s2); s3 = fdot2x(SL(q3,3), WH(15), s3);\
        half8 q4 = H8[4], q5 = H8[5];                                        \
        h2 q6 = *(const h2*)(hbuf + 48);                                     \
        s0 = fdot2x(SL(q4,0), WH(16), s0); s1 = fdot2x(SL(q4,1), WH(17), s1);\
        s2 = fdot2x(SL(q4,2), WH(18), s2); s3 = fdot2x(SL(q4,3), WH(19), s3);\
        s0 = fdot2x(SL(q5,0), WH(20), s0); s1 = fdot2x(SL(q5,1), WH(21), s1);\
        s2 = fdot2x(SL(q5,2), WH(22), s2); s3 = fdot2x(SL(q5,3), WH(23), s3);\
        s0 = fdot2x(q6,       WH(24), s0);                                   \
        float a = ((float)(XV) + (s1 + s3)) + (s0 + s2);                     \
        a = clamp26(a);                                                      \
        float e = exp2f(a);                /* v_exp_f32, no pre-mul */       \
        h = fmaf(-2.f, __builtin_amdgcn_rcpf(e + 1.f), 1.f);                 \
    }

    for (int t = 0; t < 512; t += 8) {
        // token indices read as transients; gathers issued 8 steps ahead
        __half n0 = GA(stok[t + 8]);
        __half n1 = GA(stok[t + 9]);
        __half n2 = GA(stok[t + 10]);
        __half n3 = GA(stok[t + 11]);
        __half n4 = GA(stok[t + 12]);
        __half n5 = GA(stok[t + 13]);
        __half n6 = GA(stok[t + 14]);
        __half n7 = GA(stok[t + 15]);

        RNN_STEP(x0); RNN_STEP(x1); RNN_STEP(x2); RNN_STEP(x3);
        RNN_STEP(x4); RNN_STEP(x5); RNN_STEP(x6); RNN_STEP(x7);

        x0 = n0; x1 = n1; x2 = n2; x3 = n3;
        x4 = n4; x5 = n5; x6 = n6; x7 = n7;
    }
#undef RNN_STEP
#undef SL
#undef WH
#undef GA

    // ---- head: out[b][o] = sum_h h[h] * W_fc[o][h] + b_fc[o] ----
    float hv = (lane < 50) ? h : 0.f;
    #pragma unroll
    for (int o = 0; o < 4; ++o) {
        float w = (lane < 50) ? Wfc[o * 50 + lane] : 0.f;
        float p = hv * w;
        #pragma unroll
        for (int s = 32; s > 0; s >>= 1) p += __shfl_xor(p, s, 64);
        if (lane == 0) out[b * 4 + o] = p + bfc[o];
    }
}

extern "C" void kernel_launch(void* const* d_in, const int* in_sizes, int n_in,
                              void* d_out, int out_size, void* d_ws, size_t ws_size,
                              hipStream_t stream)
{
    const int*   tokens = (const int*)d_in[0];
    const float* emb    = (const float*)d_in[1];
    const float* Wih    = (const float*)d_in[2];
    const float* Whh    = (const float*)d_in[3];
    const float* bih    = (const float*)d_in[4];
    const float* bhh    = (const float*)d_in[5];
    const float* Wfc    = (const float*)d_in[6];
    const float* bfc    = (const float*)d_in[7];

    char* ws = (char*)d_ws;
    __half* ptab   = (__half*)ws;                       // 6,400,000 B
    __half* Bfrag  = (__half*)(ws + 6400000);           //    40,960 B
    float*  bias64 = (float*)(ws + 6440960);            //       256 B
    float*  outp   = (float*)d_out;

    prep_kernel<<<41, 64, 0, stream>>>(Wih, bih, bhh, Bfrag, bias64);
    ptab_mfma<<<782, 256, 0, stream>>>(emb, Bfrag, bias64, ptab);
    rnn_kernel<<<256, 64, 0, stream>>>(tokens, ptab, Whh, Wfc, bfc, outp);
}

// Round 21
// 108.395 us; speedup vs baseline: 1.0648x; 1.0648x over previous
//
#include <hip/hip_runtime.h>
#include <hip/hip_fp16.h>

#define PTAB_STRIDE 64   // halves per row = 128 B

typedef float    f32x4 __attribute__((ext_vector_type(4)));
typedef _Float16 half8 __attribute__((ext_vector_type(8)));
typedef _Float16 h2    __attribute__((ext_vector_type(2)));

__device__ __forceinline__ h2 u2h2(unsigned int u) {
    union { unsigned int u; h2 h; } c; c.u = u; return c.h;
}

__device__ __forceinline__ float fdot2x(h2 a, h2 b, float c) {
#if __has_builtin(__builtin_amdgcn_fdot2)
    return __builtin_amdgcn_fdot2(a, b, c, false);
#else
    return c + (float)a[0] * (float)b[0] + (float)a[1] * (float)b[1];
#endif
}

__device__ __forceinline__ float clamp9(float a) {
#if __has_builtin(__builtin_amdgcn_fmed3f)
    return __builtin_amdgcn_fmed3f(a, -9.f, 9.f);
#else
    return fminf(9.f, fmaxf(-9.f, a));
#endif
}

// ---------------------------------------------------------------------------
// Kernel 0: pack B-fragments (W^T, fp16, zero-padded to K=320 x N=64) in the
// exact mfma_f32_16x16x32_f16 per-lane layout, + fused bias table.
// ---------------------------------------------------------------------------
__global__ __launch_bounds__(64) void prep_kernel(
    const float* __restrict__ Wih, const float* __restrict__ bih,
    const float* __restrict__ bhh, __half* __restrict__ Bfrag,
    float* __restrict__ bias64)
{
    const int lane = threadIdx.x;
    const int st   = blockIdx.x;
    if (st == 40) {
        if (lane < 64) bias64[lane] = (lane < 50) ? bih[lane] + bhh[lane] : 0.f;
        return;
    }
    const int s  = st >> 2, t = st & 3;
    const int n  = 16 * t + (lane & 15);
    const int kb = lane >> 4;
    half8 v;
    #pragma unroll
    for (int j = 0; j < 8; ++j) {
        const int k = 32 * s + 8 * kb + j;
        float w = 0.f;
        if (n < 50 && k < 300) w = Wih[n * 300 + k];
        v[j] = (_Float16)w;
    }
    *reinterpret_cast<half8*>(Bfrag + ((size_t)st * 64 + lane) * 8) = v;
}

// ---------------------------------------------------------------------------
// Phase 1: ptab[v][h] = fp16( dot(emb[v,:], W_ih[h,:]) + b_ih + b_hh )
// One wave per 16 vocab rows, 4 N-tile accumulators, 40 MFMAs. (proven r8)
// ---------------------------------------------------------------------------
__global__ __launch_bounds__(64) void ptab_mfma(
    const float* __restrict__ emb, const __half* __restrict__ Bfrag,
    const float* __restrict__ bias64, __half* __restrict__ ptab)
{
    const int lane = threadIdx.x;
    const int v0   = blockIdx.x * 16;
    const int m    = lane & 15;
    const int kb   = lane >> 4;
    const float* Erow = emb + (size_t)(v0 + m) * 300;
    const half8* BF   = reinterpret_cast<const half8*>(Bfrag);

    f32x4 acc[4];
    #pragma unroll
    for (int t = 0; t < 4; ++t) acc[t] = (f32x4){0.f, 0.f, 0.f, 0.f};

    #pragma unroll
    for (int s = 0; s < 9; ++s) {
        const int k0 = 32 * s + 8 * kb;
        float4 p0 = *(const float4*)(Erow + k0);
        float4 p1 = *(const float4*)(Erow + k0 + 4);
        half8 a;
        a[0] = (_Float16)p0.x; a[1] = (_Float16)p0.y;
        a[2] = (_Float16)p0.z; a[3] = (_Float16)p0.w;
        a[4] = (_Float16)p1.x; a[5] = (_Float16)p1.y;
        a[6] = (_Float16)p1.z; a[7] = (_Float16)p1.w;
        #pragma unroll
        for (int t = 0; t < 4; ++t)
            acc[t] = __builtin_amdgcn_mfma_f32_16x16x32_f16(
                a, BF[(4 * s + t) * 64 + lane], acc[t], 0, 0, 0);
    }
    {   // tail K-step s=9: k = 288..319, valid only k < 300
        half8 a;
        #pragma unroll
        for (int j = 0; j < 8; ++j) {
            const int k = 288 + 8 * kb + j;
            float e = 0.f;
            if (k < 300) e = Erow[k];
            a[j] = (_Float16)e;
        }
        #pragma unroll
        for (int t = 0; t < 4; ++t)
            acc[t] = __builtin_amdgcn_mfma_f32_16x16x32_f16(
                a, BF[(36 + t) * 64 + lane], acc[t], 0, 0, 0);
    }

    const int nn = lane & 15;
    #pragma unroll
    for (int t = 0; t < 4; ++t) {
        const float bt = bias64[16 * t + nn];
        #pragma unroll
        for (int r = 0; r < 4; ++r)
            ptab[(size_t)(v0 + 4 * kb + r) * PTAB_STRIDE + 16 * t + nn] =
                (__half)(acc[t][r] + bt);
    }
}

// ---------------------------------------------------------------------------
// Phase 2: recurrence + head. One sequence per wave, 256 waves (1/CU).
// Best-measured configuration (r16, 85.4us rnn / 400 cyc/step): LDS
// broadcast with staged 2-word read groups interleaved with 4-chain
// v_dot2_f32_f16 dots; no k-ring (tokens re-read as transients); no pins.
// Structural floor: three broadcast mechanisms (LDS RT / batched readlane /
// VALU xor-tree) and their hybrid all converge at ~400 cyc/step.
// ---------------------------------------------------------------------------
__global__ __launch_bounds__(64, 1) void rnn_kernel(
    const int* __restrict__ tokens, const __half* __restrict__ ptab,
    const float* __restrict__ Whh,
    const float* __restrict__ Wfc, const float* __restrict__ bfc,
    float* __restrict__ out)
{
    __shared__ int stok[544];
    __shared__ __align__(16) _Float16 hbuf[64];
    const int lane = threadIdx.x;
    const int b    = blockIdx.x;
    const int hc   = lane < 50 ? lane : 49;

    #pragma unroll
    for (int k = 0; k < 8; ++k)
        stok[lane + 64 * k] = tokens[b * 512 + lane + 64 * k];
    if (lane < 32) stok[512 + lane] = 0;     // pad: token 0 -> valid row
    __syncthreads();

    // W_hh row for this lane: 25 packed fp16 pairs.
    unsigned int wh_u[25];
    #pragma unroll
    for (int j = 0; j < 25; ++j) {
        float2 w2 = *(const float2*)(Whh + hc * 50 + 2 * j);
        union { h2 h; unsigned int u; } c;
        c.h = (h2){(_Float16)w2.x, (_Float16)w2.y};
        wh_u[j] = c.u;
    }

    float h = 0.f;

#define GA(T) ptab[(size_t)(T) * PTAB_STRIDE + lane]

    __half x0 = GA(stok[0]), x1 = GA(stok[1]), x2 = GA(stok[2]), x3 = GA(stok[3]);
    __half x4 = GA(stok[4]), x5 = GA(stok[5]), x6 = GA(stok[6]), x7 = GA(stok[7]);

#define SL(Q, i) __builtin_shufflevector(Q, Q, 2*(i), 2*(i)+1)
#define WH(j) u2h2(wh_u[j])

#define RNN_STEP(XV)                                                         \
    {                                                                        \
        hbuf[lane] = (_Float16)h;          /* ds_write_b16, in-order */      \
        const half8* H8 = (const half8*)hbuf;                                \
        half8 q0 = H8[0], q1 = H8[1];                                        \
        float s0 = 0.f, s1 = 0.f, s2 = 0.f, s3 = 0.f;                        \
        s0 = fdot2x(SL(q0,0), WH(0),  s0); s1 = fdot2x(SL(q0,1), WH(1),  s1);\
        s2 = fdot2x(SL(q0,2), WH(2),  s2); s3 = fdot2x(SL(q0,3), WH(3),  s3);\
        s0 = fdot2x(SL(q1,0), WH(4),  s0); s1 = fdot2x(SL(q1,1), WH(5),  s1);\
        s2 = fdot2x(SL(q1,2), WH(6),  s2); s3 = fdot2x(SL(q1,3), WH(7),  s3);\
        half8 q2 = H8[2], q3 = H8[3];                                        \
        s0 = fdot2x(SL(q2,0), WH(8),  s0); s1 = fdot2x(SL(q2,1), WH(9),  s1);\
        s2 = fdot2x(SL(q2,2), WH(10), s2); s3 = fdot2x(SL(q2,3), WH(11), s3);\
        s0 = fdot2x(SL(q3,0), WH(12), s0); s1 = fdot2x(SL(q3,1), WH(13), s1);\
        s2 = fdot2x(SL(q3,2), WH(14), s2); s3 = fdot2x(SL(q3,3), WH(15), s3);\
        half8 q4 = H8[4], q5 = H8[5];                                        \
        h2 q6 = *(const h2*)(hbuf + 48);                                     \
        s0 = fdot2x(SL(q4,0), WH(16), s0); s1 = fdot2x(SL(q4,1), WH(17), s1);\
        s2 = fdot2x(SL(q4,2), WH(18), s2); s3 = fdot2x(SL(q4,3), WH(19), s3);\
        s0 = fdot2x(SL(q5,0), WH(20), s0); s1 = fdot2x(SL(q5,1), WH(21), s1);\
        s2 = fdot2x(SL(q5,2), WH(22), s2); s3 = fdot2x(SL(q5,3), WH(23), s3);\
        s0 = fdot2x(q6,       WH(24), s0);                                   \
        float a = ((float)(XV) + (s1 + s3)) + (s0 + s2);                     \
        a = clamp9(a);                                                       \
        float e = __expf(2.f * a);                                           \
        h = fmaf(-2.f, __builtin_amdgcn_rcpf(e + 1.f), 1.f);                 \
    }

    for (int t = 0; t < 512; t += 8) {
        // token indices read as transients; gathers issued 8 steps ahead
        __half n0 = GA(stok[t + 8]);
        __half n1 = GA(stok[t + 9]);
        __half n2 = GA(stok[t + 10]);
        __half n3 = GA(stok[t + 11]);
        __half n4 = GA(stok[t + 12]);
        __half n5 = GA(stok[t + 13]);
        __half n6 = GA(stok[t + 14]);
        __half n7 = GA(stok[t + 15]);

        RNN_STEP(x0); RNN_STEP(x1); RNN_STEP(x2); RNN_STEP(x3);
        RNN_STEP(x4); RNN_STEP(x5); RNN_STEP(x6); RNN_STEP(x7);

        x0 = n0; x1 = n1; x2 = n2; x3 = n3;
        x4 = n4; x5 = n5; x6 = n6; x7 = n7;
    }
#undef RNN_STEP
#undef SL
#undef WH
#undef GA

    // ---- head: out[b][o] = sum_h h[h] * W_fc[o][h] + b_fc[o] ----
    float hv = (lane < 50) ? h : 0.f;
    #pragma unroll
    for (int o = 0; o < 4; ++o) {
        float w = (lane < 50) ? Wfc[o * 50 + lane] : 0.f;
        float p = hv * w;
        #pragma unroll
        for (int s = 32; s > 0; s >>= 1) p += __shfl_xor(p, s, 64);
        if (lane == 0) out[b * 4 + o] = p + bfc[o];
    }
}

extern "C" void kernel_launch(void* const* d_in, const int* in_sizes, int n_in,
                              void* d_out, int out_size, void* d_ws, size_t ws_size,
                              hipStream_t stream)
{
    const int*   tokens = (const int*)d_in[0];
    const float* emb    = (const float*)d_in[1];
    const float* Wih    = (const float*)d_in[2];
    const float* Whh    = (const float*)d_in[3];
    const float* bih    = (const float*)d_in[4];
    const float* bhh    = (const float*)d_in[5];
    const float* Wfc    = (const float*)d_in[6];
    const float* bfc    = (const float*)d_in[7];

    char* ws = (char*)d_ws;
    __half* ptab   = (__half*)ws;                       // 6,400,000 B
    __half* Bfrag  = (__half*)(ws + 6400000);           //    40,960 B
    float*  bias64 = (float*)(ws + 6440960);            //       256 B
    float*  outp   = (float*)d_out;

    prep_kernel<<<41, 64, 0, stream>>>(Wih, bih, bhh, Bfrag, bias64);
    ptab_mfma<<<3125, 64, 0, stream>>>(emb, Bfrag, bias64, ptab);
    rnn_kernel<<<256, 64, 0, stream>>>(tokens, ptab, Whh, Wfc, bfc, outp);
}